// Round 1
// baseline (1134.667 us; speedup 1.0000x reference)
//
#include <hip/hip_runtime.h>

#define FD 64  // feature dim

// ---- Kernel 1: in-degree via atomics (deg counted on dst) ----
__global__ void deg_kernel(const int* __restrict__ dst, float* __restrict__ deg, int E) {
    int i = blockIdx.x * blockDim.x + threadIdx.x;
    int stride = gridDim.x * blockDim.x;
    for (; i < E; i += stride) {
        atomicAdd(&deg[dst[i]], 1.0f);
    }
}

// ---- Kernel 2: dis = (deg + 1)^-1/2  (in place over deg buffer) ----
__global__ void dis_kernel(float* __restrict__ deg, int N) {
    int i = blockIdx.x * blockDim.x + threadIdx.x;
    if (i < N) {
        deg[i] = rsqrtf(deg[i] + 1.0f);
    }
}

// ---- Kernel 3: scatter-add  agg[dst] += x[src] * dis[src] ----
// 16 threads per edge, each handles 4 contiguous floats (float4 load + 4 atomics).
__global__ void scatter_kernel(const float* __restrict__ x,
                               const int* __restrict__ src,
                               const int* __restrict__ dst,
                               const float* __restrict__ dis,
                               float* __restrict__ agg, int E) {
    long long tid    = (long long)blockIdx.x * blockDim.x + threadIdx.x;
    long long total  = (long long)E * 16;
    long long stride = (long long)gridDim.x * blockDim.x;
    for (; tid < total; tid += stride) {
        int e = (int)(tid >> 4);
        int c = (int)(tid & 15);
        int s = src[e];
        int t = dst[e];
        float ds = dis[s];
        float4 v = *(const float4*)(x + (size_t)s * FD + c * 4);
        float* o = agg + (size_t)t * FD + c * 4;
        atomicAdd(o + 0, v.x * ds);
        atomicAdd(o + 1, v.y * ds);
        atomicAdd(o + 2, v.z * ds);
        atomicAdd(o + 3, v.w * ds);
    }
}

// ---- Kernel 4: out[n,:] = ((agg[n,:] + x[n,:]*dis[n]) * dis[n]) @ W^T, in place on agg/out ----
// One wave (64 lanes) per row; W transposed into LDS once per block.
// Wt[i][o] read as Wt[i][lane]: consecutive addresses per lane -> 2-way alias only (free).
// rows[w][i] read at uniform address -> broadcast (free).
__global__ __launch_bounds__(256) void final_kernel(const float* __restrict__ x,
                                                    const float* __restrict__ dis,
                                                    const float* __restrict__ W,
                                                    float* __restrict__ out, int N) {
    __shared__ float Wt[FD][FD];   // Wt[i][o] = W[o][i]
    __shared__ float rows[4][FD];

    for (int t = threadIdx.x; t < FD * FD; t += blockDim.x) {
        int o = t >> 6;
        int i = t & 63;
        Wt[i][o] = W[t];
    }

    int wave = threadIdx.x >> 6;   // 0..3
    int lane = threadIdx.x & 63;
    int n = blockIdx.x * 4 + wave;

    float a = 0.0f;
    if (n < N) {
        float dn = dis[n];
        a = (out[(size_t)n * FD + lane] + x[(size_t)n * FD + lane] * dn) * dn;
        rows[wave][lane] = a;
    }
    __syncthreads();

    if (n < N) {
        float acc = 0.0f;
        #pragma unroll
        for (int i = 0; i < FD; ++i) {
            acc += rows[wave][i] * Wt[i][lane];
        }
        out[(size_t)n * FD + lane] = acc;
    }
}

extern "C" void kernel_launch(void* const* d_in, const int* in_sizes, int n_in,
                              void* d_out, int out_size, void* d_ws, size_t ws_size,
                              hipStream_t stream) {
    const float* x   = (const float*)d_in[0];
    const int*   ei  = (const int*)d_in[1];   // [2, E] row-major: src then dst
    const float* W   = (const float*)d_in[2];

    const int N = in_sizes[0] / FD;
    const int E = in_sizes[1] / 2;
    const int* src = ei;
    const int* dst = ei + E;

    float* deg = (float*)d_ws;       // N floats; becomes dis in place
    float* agg = (float*)d_out;      // N*FD floats; accumulated, then transformed in place

    // Zero accumulators (harness does not re-poison between replays).
    hipMemsetAsync(deg, 0, (size_t)N * sizeof(float), stream);
    hipMemsetAsync(agg, 0, (size_t)N * FD * sizeof(float), stream);

    // 1) degree
    {
        int blocks = 2048;
        deg_kernel<<<blocks, 256, 0, stream>>>(dst, deg, E);
    }
    // 2) dis = rsqrt(deg+1)
    {
        int blocks = (N + 255) / 256;
        dis_kernel<<<blocks, 256, 0, stream>>>(deg, N);
    }
    // 3) scatter messages
    {
        int blocks = 2048;
        scatter_kernel<<<blocks, 256, 0, stream>>>(x, src, dst, deg, agg, E);
    }
    // 4) self-loop + normalize + linear
    {
        int blocks = (N + 3) / 4;
        final_kernel<<<blocks, 256, 0, stream>>>(x, deg, W, agg, N);
    }
}

// Round 2
// 337.375 us; speedup vs baseline: 3.3632x; 3.3632x over previous
//
#include <hip/hip_runtime.h>

#define FD 64  // feature dim

// ---------------- Kernel 1: in-degree histogram (int atomics) ----------------
__global__ void deg_kernel(const int* __restrict__ dst, int* __restrict__ degi, int E) {
    int i = blockIdx.x * blockDim.x + threadIdx.x;
    int stride = gridDim.x * blockDim.x;
    for (; i < E; i += stride) {
        atomicAdd(&degi[dst[i]], 1);
    }
}

// ---------------- Kernel 2: dis = (deg + 1)^-1/2 ----------------
__global__ void dis_kernel(const int* __restrict__ degi, float* __restrict__ dis, int N) {
    int i = blockIdx.x * blockDim.x + threadIdx.x;
    if (i < N) {
        dis[i] = rsqrtf((float)degi[i] + 1.0f);
    }
}

// ---------------- Scan (exclusive) of degi -> offs, 3-kernel hierarchical ----------------
#define SCAN_ELEMS 2048  // 256 threads x 8 elements

__global__ void scan1_kernel(const int* __restrict__ degi, int* __restrict__ offs,
                             int* __restrict__ bsums, int N) {
    __shared__ int tsum[256];
    int base = blockIdx.x * SCAN_ELEMS + threadIdx.x * 8;
    int v[8];
    int s = 0;
    #pragma unroll
    for (int k = 0; k < 8; ++k) {
        int idx = base + k;
        v[k] = (idx < N) ? degi[idx] : 0;
        s += v[k];
    }
    tsum[threadIdx.x] = s;
    __syncthreads();
    for (int off = 1; off < 256; off <<= 1) {
        int t = (threadIdx.x >= off) ? tsum[threadIdx.x - off] : 0;
        __syncthreads();
        tsum[threadIdx.x] += t;
        __syncthreads();
    }
    int excl = (threadIdx.x == 0) ? 0 : tsum[threadIdx.x - 1];
    #pragma unroll
    for (int k = 0; k < 8; ++k) {
        int idx = base + k;
        if (idx < N) offs[idx] = excl;
        excl += v[k];
    }
    if (threadIdx.x == 255) bsums[blockIdx.x] = tsum[255];
}

__global__ void scan2_kernel(int* __restrict__ bsums, int nb) {
    __shared__ int t[256];
    int v = (threadIdx.x < nb) ? bsums[threadIdx.x] : 0;
    t[threadIdx.x] = v;
    __syncthreads();
    for (int off = 1; off < 256; off <<= 1) {
        int u = (threadIdx.x >= off) ? t[threadIdx.x - off] : 0;
        __syncthreads();
        t[threadIdx.x] += u;
        __syncthreads();
    }
    if (threadIdx.x < nb) bsums[threadIdx.x] = (threadIdx.x == 0) ? 0 : t[threadIdx.x - 1];
}

__global__ void scan3_kernel(int* __restrict__ offs, const int* __restrict__ bsums, int N) {
    int i = blockIdx.x * blockDim.x + threadIdx.x;
    if (i < N) offs[i] += bsums[i / SCAN_ELEMS];
}

// ---------------- Kernel: fill buckets (CSR column array) ----------------
__global__ void fill_kernel(const int* __restrict__ src, const int* __restrict__ dst,
                            const int* __restrict__ offs, int* __restrict__ cursor,
                            int* __restrict__ bucket, int E) {
    int i = blockIdx.x * blockDim.x + threadIdx.x;
    int stride = gridDim.x * blockDim.x;
    for (; i < E; i += stride) {
        int d = dst[i];
        int pos = atomicAdd(&cursor[d], 1);
        bucket[offs[d] + pos] = src[i];
    }
}

// ---------------- Fused gather + self-loop + normalize + linear ----------------
// One wave per dst node, lane = feature index. No atomics.
__global__ __launch_bounds__(256) void gather_linear_kernel(
        const float* __restrict__ x, const int* __restrict__ offs,
        const int* __restrict__ degi, const int* __restrict__ bucket,
        const float* __restrict__ dis, const float* __restrict__ W,
        float* __restrict__ out, int N) {
    __shared__ float Wt[FD][FD];   // Wt[i][o] = W[o][i]
    __shared__ float rows[4][FD];

    for (int t = threadIdx.x; t < FD * FD; t += blockDim.x) {
        Wt[t & 63][t >> 6] = W[t];
    }

    int wave = threadIdx.x >> 6;
    int lane = threadIdx.x & 63;
    int n = blockIdx.x * 4 + wave;

    if (n < N) {
        int start = offs[n];
        int deg   = degi[n];
        int end   = start + deg;
        float acc = 0.0f;
        int j = start;
        for (; j + 1 < end; j += 2) {  // 2x unroll: two gathers in flight
            int s0 = bucket[j];
            int s1 = bucket[j + 1];
            float d0 = dis[s0];
            float d1 = dis[s1];
            float v0 = x[(size_t)s0 * FD + lane];
            float v1 = x[(size_t)s1 * FD + lane];
            acc += v0 * d0;
            acc += v1 * d1;
        }
        if (j < end) {
            int s = bucket[j];
            acc += x[(size_t)s * FD + lane] * dis[s];
        }
        float dn = dis[n];
        rows[wave][lane] = (acc + x[(size_t)n * FD + lane] * dn) * dn;
    }
    __syncthreads();

    if (n < N) {
        float o = 0.0f;
        #pragma unroll
        for (int i = 0; i < FD; ++i) {
            o += rows[wave][i] * Wt[i][lane];
        }
        out[(size_t)n * FD + lane] = o;
    }
}

extern "C" void kernel_launch(void* const* d_in, const int* in_sizes, int n_in,
                              void* d_out, int out_size, void* d_ws, size_t ws_size,
                              hipStream_t stream) {
    const float* x  = (const float*)d_in[0];
    const int*   ei = (const int*)d_in[1];   // [2, E]: src row then dst row
    const float* W  = (const float*)d_in[2];

    const int N = in_sizes[0] / FD;
    const int E = in_sizes[1] / 2;
    const int* src = ei;
    const int* dst = ei + E;

    // Workspace layout (all 4-byte types):
    //   degi[N] | dis[N] | offs[N] | cursor[N] | bsums[1024] | bucket[E]
    char* ws = (char*)d_ws;
    int*   degi   = (int*)ws;                      ws += (size_t)N * 4;
    float* dis    = (float*)ws;                    ws += (size_t)N * 4;
    int*   offs   = (int*)ws;                      ws += (size_t)N * 4;
    int*   cursor = (int*)ws;                      ws += (size_t)N * 4;
    int*   bsums  = (int*)ws;                      ws += 1024 * 4;
    int*   bucket = (int*)ws;

    float* out = (float*)d_out;

    hipMemsetAsync(degi,   0, (size_t)N * 4, stream);
    hipMemsetAsync(cursor, 0, (size_t)N * 4, stream);

    // 1) degree histogram
    deg_kernel<<<2048, 256, 0, stream>>>(dst, degi, E);
    // 2) dis
    dis_kernel<<<(N + 255) / 256, 256, 0, stream>>>(degi, dis, N);
    // 3) exclusive scan degi -> offs
    int nb = (N + SCAN_ELEMS - 1) / SCAN_ELEMS;
    scan1_kernel<<<nb, 256, 0, stream>>>(degi, offs, bsums, N);
    scan2_kernel<<<1, 256, 0, stream>>>(bsums, nb);
    scan3_kernel<<<(N + 255) / 256, 256, 0, stream>>>(offs, bsums, N);
    // 4) fill CSR buckets
    fill_kernel<<<2048, 256, 0, stream>>>(src, dst, offs, cursor, bucket, E);
    // 5) fused gather + self-loop + normalize + linear
    gather_linear_kernel<<<(N + 3) / 4, 256, 0, stream>>>(x, offs, degi, bucket, dis, W, out, N);
}